// Round 1
// 1013.155 us; speedup vs baseline: 1.1135x; 1.1135x over previous
//
#include <hip/hip_runtime.h>

typedef __bf16 bf16_t;
typedef bf16_t bf16x8 __attribute__((ext_vector_type(8)));
typedef bf16_t bf16x4 __attribute__((ext_vector_type(4)));
typedef float floatx4 __attribute__((ext_vector_type(4)));

#define T_TOKENS 8192
#define HIDDEN 1024
#define FFN 4096
#define NE 8
#define PAIRS 16384   // T_TOKENS * TOP_K
#define NTILES 136    // max row tiles: PAIRS/128 + NE partials
#define BK 64

// async global->LDS, 16B per lane; LDS dest is wave-uniform base + lane*16
#define GLD16(gp, lp) __builtin_amdgcn_global_load_lds( \
    (const __attribute__((address_space(1))) void*)(gp), \
    (__attribute__((address_space(3))) void*)(lp), 16, 0, 0)

// ------------------------------------------- gate + top2 (+ fused x->bf16)
__global__ __launch_bounds__(256) void gate_kernel(
    const float* __restrict__ x, const float* __restrict__ gw,
    const float* __restrict__ gb, unsigned* __restrict__ top2,
    int* __restrict__ counts, bf16_t* __restrict__ xb)
{
    const int lane = threadIdx.x & 63;
    const int wid  = threadIdx.x >> 6;
    const int t    = blockIdx.x * 4 + wid;
    const float4* xr = (const float4*)(x + (size_t)t * HIDDEN);
    bf16_t* xo = xb + (size_t)t * HIDDEN;

    float s[NE];
#pragma unroll
    for (int e = 0; e < NE; ++e) s[e] = 0.f;
#pragma unroll
    for (int ii = 0; ii < 4; ++ii) {
        const int i = ii * 64 + lane;
        float4 v = xr[i];
        bf16x4 b;
        b[0] = (bf16_t)v.x; b[1] = (bf16_t)v.y; b[2] = (bf16_t)v.z; b[3] = (bf16_t)v.w;
        *(bf16x4*)(xo + i * 4) = b;
        const float* g = gw + (size_t)i * 32;   // (i*4+j)*NE
#pragma unroll
        for (int j = 0; j < 4; ++j) {
            const float xv = (&v.x)[j];
#pragma unroll
            for (int e = 0; e < NE; ++e) s[e] += xv * g[j * 8 + e];
        }
    }
#pragma unroll
    for (int e = 0; e < NE; ++e) {
#pragma unroll
        for (int off = 32; off > 0; off >>= 1) s[e] += __shfl_xor(s[e], off, 64);
    }
    if (lane == 0) {
        float v1 = -1e30f, v2 = -1e30f;
        int i1 = 0, i2 = 0;
#pragma unroll
        for (int e = 0; e < NE; ++e) {
            float v = s[e] + gb[e];
            if (v > v1)      { v2 = v1; i2 = i1; v1 = v; i1 = e; }
            else if (v > v2) { v2 = v;  i2 = e; }
        }
        top2[t] = (unsigned)(i1 | (i2 << 4));
        atomicAdd(&counts[i1], 1);
        atomicAdd(&counts[i2], 1);
    }
}

// -------------------------------------- prefix offsets + row-tile table
__global__ void offsets_kernel(const int* __restrict__ counts,
                               int* __restrict__ offs,
                               int* __restrict__ tinfo)
{
    int acc = 0, nt = 0;
    for (int e = 0; e < NE; ++e) {
        offs[e] = acc;
        int n = counts[e];
        for (int r = 0; r < n; r += 128) tinfo[nt++] = e | ((r >> 7) << 4);
        acc += n;
    }
    for (; nt < NTILES; ++nt) tinfo[nt] = (65535 << 4);  // row0 huge -> block exits
}

// ----------------------- scatter: token lists (u16)
__global__ __launch_bounds__(256) void scatter_kernel(
    const unsigned* __restrict__ top2, const int* __restrict__ offs,
    int* __restrict__ fill, unsigned short* __restrict__ tok16)
{
    const int t = blockIdx.x * 256 + threadIdx.x;
    const unsigned v = top2[t];
    const int e1 = v & 15, e2 = (v >> 4) & 15;
    tok16[offs[e1] + atomicAdd(&fill[e1], 1)] = (unsigned short)t;
    tok16[offs[e2] + atomicAdd(&fill[e2], 1)] = (unsigned short)t;
}

// ------------------------------- fp32 [E][R][C] -> bf16 [E][C][R] transpose
__global__ __launch_bounds__(256) void wtrans_kernel(
    const float* __restrict__ in, bf16_t* __restrict__ out, int R, int C)
{
    __shared__ bf16_t L[64][68];
    const int e  = blockIdx.z;
    const int r0 = blockIdx.y * 64;
    const int c0 = blockIdx.x * 64;
    const float* ip = in + ((size_t)e * R + r0) * C + c0;
    bf16_t* op = out + ((size_t)e * C + c0) * R + r0;
    const int tid = threadIdx.x;
    const int lr = tid >> 4, lc4 = tid & 15;
#pragma unroll
    for (int p = 0; p < 4; ++p) {
        int r = p * 16 + lr;
        float4 v = *(const float4*)(ip + (size_t)r * C + lc4 * 4);
        bf16x4 b;
        b[0] = (bf16_t)v.x; b[1] = (bf16_t)v.y; b[2] = (bf16_t)v.z; b[3] = (bf16_t)v.w;
        *(bf16x4*)&L[r][lc4 * 4] = b;
    }
    __syncthreads();
#pragma unroll
    for (int p = 0; p < 4; ++p) {
        int c  = p * 16 + lr;
        int rr = lc4 * 4;
        bf16x4 b;
        b[0] = L[rr + 0][c]; b[1] = L[rr + 1][c];
        b[2] = L[rr + 2][c]; b[3] = L[rr + 3][c];
        *(bf16x4*)(op + (size_t)c * R + rr) = b;
    }
}

// --------------------------------------------------------- GEMM1 (BK=64)
// h1[slot][f] = relu(xb[tok[slot]] @ w1t[e]^T + b1[e])
__global__ __launch_bounds__(256, 3) void moe_gemm1(
    const bf16_t* __restrict__ xb, const bf16_t* __restrict__ w1t,
    const float* __restrict__ b1, const int* __restrict__ counts,
    const int* __restrict__ offs, const unsigned short* __restrict__ tok16,
    const int* __restrict__ tinfo, bf16_t* __restrict__ h1)
{
    // XCD-grouping swizzle: contiguous x-major chunk per XCD (nwg % 8 == 0)
    const int nx = gridDim.x;
    const int hw = blockIdx.y * nx + blockIdx.x;
    const int chunk = (nx * gridDim.y) >> 3;
    const int l  = (hw & 7) * chunk + (hw >> 3);
    const int bx = l % nx;
    const int by = l / nx;

    const int info = tinfo[by];
    const int e    = info & 15;
    const int row0 = (info >> 4) << 7;
    const int n_e  = counts[e];
    if (row0 >= n_e) return;
    const int seg   = offs[e];
    const int fcol0 = bx * 128;

    __shared__ bf16_t S[128 * 128];      // As | Bs during loop, repack after
    bf16_t* As = S;
    bf16_t* Bs = S + 128 * BK;

    const int tid  = threadIdx.x;
    const int wid  = tid >> 6, lane = tid & 63;
    const int wm   = wid & 1,  wn   = wid >> 1;
    const int quad = lane >> 4, lrow = lane & 15;

    // staging pointers: source granule pre-swizzled with ko ^ (row&7)
    const bf16_t* pA[4]; const bf16_t* pB[4];
#pragma unroll
    for (int q = 0; q < 4; ++q) {
        int slot = q * 256 + tid;
        int arow = slot >> 3, ko = slot & 7;
        int kos  = ko ^ (arow & 7);
        int ridx = row0 + arow; if (ridx > n_e - 1) ridx = n_e - 1;
        pA[q] = xb + (size_t)tok16[seg + ridx] * HIDDEN + kos * 8;
        pB[q] = w1t + ((size_t)e * FFN + fcol0 + arow) * HIDDEN + kos * 8;
    }

    floatx4 acc[4][4];
#pragma unroll
    for (int i = 0; i < 4; ++i)
#pragma unroll
        for (int j = 0; j < 4; ++j) acc[i][j] = (floatx4){0.f, 0.f, 0.f, 0.f};

    for (int k0 = 0; k0 < HIDDEN; k0 += BK) {
#pragma unroll
        for (int q = 0; q < 4; ++q) {
            GLD16(pA[q], As + (q * 256 + wid * 64) * 8);
            GLD16(pB[q], Bs + (q * 256 + wid * 64) * 8);
            pA[q] += BK; pB[q] += BK;
        }
        __syncthreads();
#pragma unroll
        for (int h = 0; h < 2; ++h) {
            bf16x8 af[4], bfr[4];
#pragma unroll
            for (int mi = 0; mi < 4; ++mi) {
                int r = wm * 64 + mi * 16 + lrow;
                int g = (h * 4 + quad) ^ (r & 7);
                af[mi] = *(const bf16x8*)&As[(r << 6) + (g << 3)];
            }
#pragma unroll
            for (int ni = 0; ni < 4; ++ni) {
                int r = wn * 64 + ni * 16 + lrow;
                int g = (h * 4 + quad) ^ (r & 7);
                bfr[ni] = *(const bf16x8*)&Bs[(r << 6) + (g << 3)];
            }
#pragma unroll
            for (int mi = 0; mi < 4; ++mi)
#pragma unroll
                for (int ni = 0; ni < 4; ++ni)
                    acc[mi][ni] = __builtin_amdgcn_mfma_f32_16x16x32_bf16(
                        af[mi], bfr[ni], acc[mi][ni], 0, 0, 0);
        }
        __syncthreads();
    }

    // epilogue: bias+relu -> LDS bf16 [128][128] -> coalesced 16B stores
#pragma unroll
    for (int ni = 0; ni < 4; ++ni) {
        const int col = wn * 64 + ni * 16 + lrow;
        const float bias = b1[(size_t)e * FFN + fcol0 + col];
#pragma unroll
        for (int mi = 0; mi < 4; ++mi)
#pragma unroll
            for (int r = 0; r < 4; ++r) {
                int row = wm * 64 + mi * 16 + quad * 4 + r;
                float v = acc[mi][ni][r] + bias;
                v = v > 0.f ? v : 0.f;
                S[row * 128 + col] = (bf16_t)v;
            }
    }
    __syncthreads();
#pragma unroll
    for (int i = 0; i < 8; ++i) {
        int g16 = i * 256 + tid;          // 2048 granules of 16B
        int row = g16 >> 4;
        int ce  = (g16 & 15) * 8;
        if (row0 + row < n_e)
            *(bf16x8*)(h1 + (size_t)(seg + row0 + row) * FFN + fcol0 + ce) =
                *(const bf16x8*)&S[row * 128 + ce];
    }
}

// -------------------- GEMM2 (BK=64) + fused combine via atomicAdd into out
__global__ __launch_bounds__(256, 3) void moe_gemm2(
    const bf16_t* __restrict__ h1, const bf16_t* __restrict__ w2t,
    const float* __restrict__ b2, const int* __restrict__ counts,
    const int* __restrict__ offs, const unsigned short* __restrict__ tok16,
    const int* __restrict__ tinfo, float* __restrict__ out)
{
    const int nx = gridDim.x;
    const int hw = blockIdx.y * nx + blockIdx.x;
    const int chunk = (nx * gridDim.y) >> 3;
    const int l  = (hw & 7) * chunk + (hw >> 3);
    const int bx = l % nx;
    const int by = l / nx;

    const int info = tinfo[by];
    const int e    = info & 15;
    const int row0 = (info >> 4) << 7;
    const int n_e  = counts[e];
    if (row0 >= n_e) return;
    const int seg   = offs[e];
    const int hcol0 = bx * 128;

    __shared__ bf16_t As[128 * BK];
    __shared__ bf16_t Bs[128 * BK];

    const int tid  = threadIdx.x;
    const int wid  = tid >> 6, lane = tid & 63;
    const int wm   = wid & 1,  wn   = wid >> 1;
    const int quad = lane >> 4, lrow = lane & 15;

    const bf16_t* pA[4]; const bf16_t* pB[4];
#pragma unroll
    for (int q = 0; q < 4; ++q) {
        int slot = q * 256 + tid;
        int arow = slot >> 3, ko = slot & 7;
        int kos  = ko ^ (arow & 7);
        int ridx = row0 + arow; if (ridx > n_e - 1) ridx = n_e - 1;
        pA[q] = h1 + (size_t)(seg + ridx) * FFN + kos * 8;
        pB[q] = w2t + ((size_t)e * HIDDEN + hcol0 + arow) * FFN + kos * 8;
    }

    floatx4 acc[4][4];
#pragma unroll
    for (int i = 0; i < 4; ++i)
#pragma unroll
        for (int j = 0; j < 4; ++j) acc[i][j] = (floatx4){0.f, 0.f, 0.f, 0.f};

    for (int k0 = 0; k0 < FFN; k0 += BK) {
#pragma unroll
        for (int q = 0; q < 4; ++q) {
            GLD16(pA[q], As + (q * 256 + wid * 64) * 8);
            GLD16(pB[q], Bs + (q * 256 + wid * 64) * 8);
            pA[q] += BK; pB[q] += BK;
        }
        __syncthreads();
#pragma unroll
        for (int h = 0; h < 2; ++h) {
            bf16x8 af[4], bfr[4];
#pragma unroll
            for (int mi = 0; mi < 4; ++mi) {
                int r = wm * 64 + mi * 16 + lrow;
                int g = (h * 4 + quad) ^ (r & 7);
                af[mi] = *(const bf16x8*)&As[(r << 6) + (g << 3)];
            }
#pragma unroll
            for (int ni = 0; ni < 4; ++ni) {
                int r = wn * 64 + ni * 16 + lrow;
                int g = (h * 4 + quad) ^ (r & 7);
                bfr[ni] = *(const bf16x8*)&Bs[(r << 6) + (g << 3)];
            }
#pragma unroll
            for (int mi = 0; mi < 4; ++mi)
#pragma unroll
                for (int ni = 0; ni < 4; ++ni)
                    acc[mi][ni] = __builtin_amdgcn_mfma_f32_16x16x32_bf16(
                        af[mi], bfr[ni], acc[mi][ni], 0, 0, 0);
        }
        __syncthreads();
    }

    // fused combine: out[tok] += acc + b2  (exactly 2 adds per element)
    int tokr[4][4];
#pragma unroll
    for (int mi = 0; mi < 4; ++mi)
#pragma unroll
        for (int r = 0; r < 4; ++r) {
            int row = wm * 64 + mi * 16 + quad * 4 + r;
            tokr[mi][r] = (row0 + row < n_e) ? (int)tok16[seg + row0 + row] : -1;
        }
#pragma unroll
    for (int ni = 0; ni < 4; ++ni) {
        const int col = wn * 64 + ni * 16 + lrow;
        const float bias = b2[(size_t)e * HIDDEN + hcol0 + col];
#pragma unroll
        for (int mi = 0; mi < 4; ++mi)
#pragma unroll
            for (int r = 0; r < 4; ++r) {
                if (tokr[mi][r] >= 0)
                    atomicAdd(out + (size_t)tokr[mi][r] * HIDDEN + hcol0 + col,
                              acc[mi][ni][r] + bias);
            }
    }
}

// -------------------------------------------------------------------- launch
extern "C" void kernel_launch(void* const* d_in, const int* in_sizes, int n_in,
                              void* d_out, int out_size, void* d_ws, size_t ws_size,
                              hipStream_t stream)
{
    const float* x      = (const float*)d_in[0];
    const float* gate_w = (const float*)d_in[1];
    const float* gate_b = (const float*)d_in[2];
    const float* w1     = (const float*)d_in[3];
    const float* b1     = (const float*)d_in[4];
    const float* w2     = (const float*)d_in[5];
    const float* b2     = (const float*)d_in[6];
    float* out = (float*)d_out;

    char* ws = (char*)d_ws;
    int*      counts = (int*)(ws + 0);       // 32 B
    int*      fill   = (int*)(ws + 32);      // 32 B
    int*      offs   = (int*)(ws + 64);      // 32 B
    int*      tinfo  = (int*)(ws + 96);      // 136*4 = 544 B -> 640
    unsigned* top2   = (unsigned*)(ws + 640);                     // 32 KB
    unsigned short* tok16 = (unsigned short*)(ws + 640 + 32768);  // 32 KB
    const size_t o_base = 98560;

    const size_t sz_xb  = (size_t)T_TOKENS * HIDDEN * 2;   // 16 MB
    const size_t sz_w1t = (size_t)NE * FFN * HIDDEN * 2;   // 64 MB
    const size_t sz_w2t = (size_t)NE * HIDDEN * FFN * 2;   // 64 MB
    const size_t sz_h1  = (size_t)PAIRS * FFN * 2;         // 128 MB
    const size_t need = o_base + sz_xb + sz_w1t + sz_w2t + sz_h1;
    if (ws_size < need) return;

    bf16_t* xb  = (bf16_t*)(ws + o_base);
    bf16_t* w1t = (bf16_t*)(ws + o_base + sz_xb);
    bf16_t* w2t = (bf16_t*)(ws + o_base + sz_xb + sz_w1t);
    bf16_t* h1  = (bf16_t*)(ws + o_base + sz_xb + sz_w1t + sz_w2t);

    hipMemsetAsync(ws, 0, 96, stream);  // counts/fill/offs
    hipMemsetAsync(out, 0, (size_t)T_TOKENS * HIDDEN * sizeof(float), stream);

    gate_kernel<<<T_TOKENS / 4, 256, 0, stream>>>(x, gate_w, gate_b, top2, counts, xb);
    offsets_kernel<<<1, 1, 0, stream>>>(counts, offs, tinfo);
    scatter_kernel<<<T_TOKENS / 256, 256, 0, stream>>>(top2, offs, fill, tok16);

    wtrans_kernel<<<dim3(FFN / 64, HIDDEN / 64, NE), 256, 0, stream>>>(w1, w1t, HIDDEN, FFN);
    wtrans_kernel<<<dim3(HIDDEN / 64, FFN / 64, NE), 256, 0, stream>>>(w2, w2t, FFN, HIDDEN);

    moe_gemm1<<<dim3(FFN / 128, NTILES), 256, 0, stream>>>(
        xb, w1t, b1, counts, offs, tok16, tinfo, h1);
    moe_gemm2<<<dim3(HIDDEN / 128, NTILES), 256, 0, stream>>>(
        h1, w2t, b2, counts, offs, tok16, tinfo, out);
}